// Round 1
// baseline (518.747 us; speedup 1.0000x reference)
//
#include <hip/hip_runtime.h>
#include <math.h>

#define NB 2048
#define NL 256
#define NH 512

__device__ __forceinline__ float wsum(float v){
  #pragma unroll
  for (int o = 32; o; o >>= 1) v += __shfl_xor(v, o);
  return v;
}
__device__ __forceinline__ float wmax(float v){
  #pragma unroll
  for (int o = 32; o; o >>= 1) v = fmaxf(v, __shfl_xor(v, o));
  return v;
}

// ---------------------------------------------------------------------------
// k1: embedded = LN(x*emb_W+emb_b); logits = [e,h]@attn_W+b; softmax.
// 4 batches per block, 256 threads (4 waves). Wave w owns batch b0+w for the
// per-batch phases; all 256 threads cooperate on the logits GEMM (1 l-col per
// thread, 4 batches accumulated in registers, attn_W is L2-resident).
// ---------------------------------------------------------------------------
__global__ __launch_bounds__(256)
void k_embed_attn(const float* __restrict__ x, const float* __restrict__ hidden,
                  const float* __restrict__ emb_W, const float* __restrict__ emb_b,
                  const float* __restrict__ attn_W, const float* __restrict__ attn_b,
                  float* __restrict__ e_out, float* __restrict__ attn_out)
{
  __shared__ __align__(16) float c[4][2*NH];   // [batch][concat(e,hidden)] 16 KB
  __shared__ float lgt[4][NL];                 // 4 KB
  const int tid = threadIdx.x, wv = tid >> 6, lane = tid & 63;
  const int b0 = blockIdx.x * 4;

  { // phase 1: embed + layernorm, wave wv -> batch b0+wv
    const int b = b0 + wv;
    const float xv = x[b];
    float ev[8]; float s = 0.f, sq = 0.f;
    #pragma unroll
    for (int k = 0; k < 8; ++k) {
      int h = lane + 64*k;
      float e = fmaf(xv, emb_W[h], emb_b[h]);
      ev[k] = e; s += e; sq += e*e;
    }
    s = wsum(s); sq = wsum(sq);
    float mu = s * (1.0f/NH);
    float var = sq * (1.0f/NH) - mu*mu;
    float rs = rsqrtf(var + 1e-5f);
    #pragma unroll
    for (int k = 0; k < 8; ++k) {
      int h = lane + 64*k;
      float e = (ev[k] - mu) * rs;
      c[wv][h] = e;
      e_out[(size_t)b*NH + h] = e;
      c[wv][NH + h] = hidden[(size_t)b*NH + h];
    }
  }
  __syncthreads();

  { // phase 2: logits — thread owns column l for all 4 batches
    const int l = tid;
    float acc0, acc1, acc2, acc3;
    acc0 = acc1 = acc2 = acc3 = attn_b[l];
    const float4* c0 = (const float4*)&c[0][0];
    const float4* c1 = (const float4*)&c[1][0];
    const float4* c2 = (const float4*)&c[2][0];
    const float4* c3 = (const float4*)&c[3][0];
    for (int rq = 0; rq < (2*NH)/4; ++rq) {
      const int r = rq * 4;
      float w0 = attn_W[(size_t)(r+0)*NL + l];
      float w1 = attn_W[(size_t)(r+1)*NL + l];
      float w2 = attn_W[(size_t)(r+2)*NL + l];
      float w3 = attn_W[(size_t)(r+3)*NL + l];
      float4 v;
      v = c0[rq]; acc0 = fmaf(v.x,w0,fmaf(v.y,w1,fmaf(v.z,w2,fmaf(v.w,w3,acc0))));
      v = c1[rq]; acc1 = fmaf(v.x,w0,fmaf(v.y,w1,fmaf(v.z,w2,fmaf(v.w,w3,acc1))));
      v = c2[rq]; acc2 = fmaf(v.x,w0,fmaf(v.y,w1,fmaf(v.z,w2,fmaf(v.w,w3,acc2))));
      v = c3[rq]; acc3 = fmaf(v.x,w0,fmaf(v.y,w1,fmaf(v.z,w2,fmaf(v.w,w3,acc3))));
    }
    lgt[0][l] = acc0; lgt[1][l] = acc1; lgt[2][l] = acc2; lgt[3][l] = acc3;
  }
  __syncthreads();

  { // phase 3: softmax over L=256, wave wv -> batch b0+wv (4 vals/lane)
    const int b = b0 + wv;
    float v0 = lgt[wv][lane], v1 = lgt[wv][lane+64];
    float v2 = lgt[wv][lane+128], v3 = lgt[wv][lane+192];
    float m = fmaxf(fmaxf(v0,v1), fmaxf(v2,v3));
    m = wmax(m);
    v0 = expf(v0-m); v1 = expf(v1-m); v2 = expf(v2-m); v3 = expf(v3-m);
    float inv = 1.0f / wsum(v0+v1+v2+v3);
    size_t base = (size_t)b*NL;
    attn_out[base+lane]     = v0*inv;
    attn_out[base+lane+64]  = v1*inv;
    attn_out[base+lane+128] = v2*inv;
    attn_out[base+lane+192] = v3*inv;
  }
}

// ---------------------------------------------------------------------------
// k2: attn_applied[b,:] = sum_l w[b,l] * enc[b,l,:]. THE memory-bound kernel:
// 1.07 GB of encoder_outputs streamed once. 2048 blocks (8/CU) x 128 threads,
// float4 (16 B/lane) coalesced loads, weight broadcast from LDS.
// ---------------------------------------------------------------------------
__global__ __launch_bounds__(128)
void k_attn_apply(const float* __restrict__ enc, const float* __restrict__ aw,
                  float* __restrict__ a_out)
{
  __shared__ float w[NL];
  const int tid = threadIdx.x;
  const int b = blockIdx.x;
  for (int l = tid; l < NL; l += 128) w[l] = aw[(size_t)b*NL + l];
  __syncthreads();
  const float4* ep = (const float4*)(enc + (size_t)b*NL*NH);
  float4 acc = {0.f,0.f,0.f,0.f};
  #pragma unroll 4
  for (int l = 0; l < NL; ++l) {
    float wv = w[l];
    float4 e = ep[l*(NH/4) + tid];
    acc.x = fmaf(wv,e.x,acc.x); acc.y = fmaf(wv,e.y,acc.y);
    acc.z = fmaf(wv,e.z,acc.z); acc.w = fmaf(wv,e.w,acc.w);
  }
  ((float4*)(a_out + (size_t)b*NH))[tid] = acc;
}

// ---------------------------------------------------------------------------
// k3: xt = relu([e, a] @ comb_W + comb_b). 8 batches/block, 512 threads
// (1 output col each), comb_W (2 MB) streamed from L2, activations in LDS.
// NOTE: xt_out aliases a_in (d_ws reuse) — all a_in reads land in LDS before
// __syncthreads(); writes happen last and are block-local. Safe.
// ---------------------------------------------------------------------------
__global__ __launch_bounds__(512)
void k_comb(const float* e_in, const float* a_in,
            const float* __restrict__ comb_W, const float* __restrict__ comb_b,
            float* xt_out)
{
  __shared__ __align__(16) float ebuf[8][NH];  // 16 KB
  __shared__ __align__(16) float abuf[8][NH];  // 16 KB
  const int tid = threadIdx.x;
  const int b0 = blockIdx.x * 8;
  #pragma unroll
  for (int i = 0; i < 8; ++i) {
    ebuf[i][tid] = e_in[(size_t)(b0+i)*NH + tid];
    abuf[i][tid] = a_in[(size_t)(b0+i)*NH + tid];
  }
  __syncthreads();
  float acc[8];
  {
    float bias = comb_b[tid];
    #pragma unroll
    for (int i = 0; i < 8; ++i) acc[i] = bias;
  }
  for (int rq = 0; rq < NH/4; ++rq) {       // rows 0..511: e part
    const int r = rq*4;
    float w0 = comb_W[(size_t)(r+0)*NH + tid];
    float w1 = comb_W[(size_t)(r+1)*NH + tid];
    float w2 = comb_W[(size_t)(r+2)*NH + tid];
    float w3 = comb_W[(size_t)(r+3)*NH + tid];
    #pragma unroll
    for (int i = 0; i < 8; ++i) {
      float4 v = ((const float4*)ebuf[i])[rq];
      acc[i] = fmaf(v.x,w0,fmaf(v.y,w1,fmaf(v.z,w2,fmaf(v.w,w3,acc[i]))));
    }
  }
  for (int rq = 0; rq < NH/4; ++rq) {       // rows 512..1023: a part
    const int r = rq*4;
    float w0 = comb_W[(size_t)(NH+r+0)*NH + tid];
    float w1 = comb_W[(size_t)(NH+r+1)*NH + tid];
    float w2 = comb_W[(size_t)(NH+r+2)*NH + tid];
    float w3 = comb_W[(size_t)(NH+r+3)*NH + tid];
    #pragma unroll
    for (int i = 0; i < 8; ++i) {
      float4 v = ((const float4*)abuf[i])[rq];
      acc[i] = fmaf(v.x,w0,fmaf(v.y,w1,fmaf(v.z,w2,fmaf(v.w,w3,acc[i]))));
    }
  }
  #pragma unroll
  for (int i = 0; i < 8; ++i)
    xt_out[(size_t)(b0+i)*NH + tid] = fmaxf(acc[i], 0.f);
}

// ---------------------------------------------------------------------------
// k4: GRU cell (both 512x1536 GEMMs fused) + gates + h_new + output proj.
// 8 batches/block, 512 threads (1 h-col each). Wih/Whh (6 MB) streamed.
// ---------------------------------------------------------------------------
__global__ __launch_bounds__(512)
void k_gru(const float* __restrict__ xt, const float* __restrict__ hidden,
           const float* __restrict__ Wih, const float* __restrict__ Whh,
           const float* __restrict__ bih, const float* __restrict__ bhh,
           const float* __restrict__ out_W, const float* __restrict__ out_b,
           float* __restrict__ out0, float* __restrict__ h_out)
{
  __shared__ __align__(16) float xbuf[8][NH];  // 16 KB
  __shared__ __align__(16) float hbuf[8][NH];  // 16 KB
  __shared__ float red[8][8];
  const int tid = threadIdx.x;
  const int b0 = blockIdx.x * 8;
  #pragma unroll
  for (int i = 0; i < 8; ++i) {
    xbuf[i][tid] = xt[(size_t)(b0+i)*NH + tid];
    hbuf[i][tid] = hidden[(size_t)(b0+i)*NH + tid];
  }
  __syncthreads();

  float sr[8], sz[8], si[8], sh[8];
  {
    float br = bih[tid] + bhh[tid];
    float bz = bih[NH+tid] + bhh[NH+tid];
    float bi = bih[2*NH+tid];
    float bh = bhh[2*NH+tid];
    #pragma unroll
    for (int i = 0; i < 8; ++i) { sr[i]=br; sz[i]=bz; si[i]=bi; sh[i]=bh; }
  }

  for (int hq = 0; hq < NH/4; ++hq) {
    float wir[4], wiz[4], win[4], whr[4], whz[4], whn[4];
    #pragma unroll
    for (int k = 0; k < 4; ++k) {
      const float* Ri = Wih + (size_t)(hq*4+k)*(3*NH);
      const float* Rh = Whh + (size_t)(hq*4+k)*(3*NH);
      wir[k]=Ri[tid]; wiz[k]=Ri[NH+tid]; win[k]=Ri[2*NH+tid];
      whr[k]=Rh[tid]; whz[k]=Rh[NH+tid]; whn[k]=Rh[2*NH+tid];
    }
    #pragma unroll
    for (int i = 0; i < 8; ++i) {
      float4 xv = ((const float4*)xbuf[i])[hq];
      float4 hv = ((const float4*)hbuf[i])[hq];
      float r0=sr[i], z0=sz[i], i0=si[i], h0=sh[i];
      r0=fmaf(xv.x,wir[0],r0); r0=fmaf(hv.x,whr[0],r0);
      r0=fmaf(xv.y,wir[1],r0); r0=fmaf(hv.y,whr[1],r0);
      r0=fmaf(xv.z,wir[2],r0); r0=fmaf(hv.z,whr[2],r0);
      r0=fmaf(xv.w,wir[3],r0); r0=fmaf(hv.w,whr[3],r0);
      z0=fmaf(xv.x,wiz[0],z0); z0=fmaf(hv.x,whz[0],z0);
      z0=fmaf(xv.y,wiz[1],z0); z0=fmaf(hv.y,whz[1],z0);
      z0=fmaf(xv.z,wiz[2],z0); z0=fmaf(hv.z,whz[2],z0);
      z0=fmaf(xv.w,wiz[3],z0); z0=fmaf(hv.w,whz[3],z0);
      i0=fmaf(xv.x,win[0],i0); i0=fmaf(xv.y,win[1],i0);
      i0=fmaf(xv.z,win[2],i0); i0=fmaf(xv.w,win[3],i0);
      h0=fmaf(hv.x,whn[0],h0); h0=fmaf(hv.y,whn[1],h0);
      h0=fmaf(hv.z,whn[2],h0); h0=fmaf(hv.w,whn[3],h0);
      sr[i]=r0; sz[i]=z0; si[i]=i0; sh[i]=h0;
    }
  }

  const float ow = out_W[tid];
  float partial[8];
  #pragma unroll
  for (int i = 0; i < 8; ++i) {
    float r = 1.f/(1.f + expf(-sr[i]));
    float z = 1.f/(1.f + expf(-sz[i]));
    float n = tanhf(fmaf(r, sh[i], si[i]));
    float h0v = hbuf[i][tid];
    float hn = fmaf(z, h0v - n, n);           // (1-z)*n + z*h0
    h_out[(size_t)(b0+i)*NH + tid] = hn;
    partial[i] = hn * ow;
  }
  const int wv = tid >> 6, lane = tid & 63;
  #pragma unroll
  for (int i = 0; i < 8; ++i) {
    float v = wsum(partial[i]);
    if (lane == 0) red[i][wv] = v;
  }
  __syncthreads();
  if (tid < 8) {
    float s = 0.f;
    #pragma unroll
    for (int w = 0; w < 8; ++w) s += red[tid][w];
    out0[b0 + tid] = s + out_b[0];
  }
}

// ---------------------------------------------------------------------------
extern "C" void kernel_launch(void* const* d_in, const int* in_sizes, int n_in,
                              void* d_out, int out_size, void* d_ws, size_t ws_size,
                              hipStream_t stream)
{
  const float* x      = (const float*)d_in[0];
  const float* hidden = (const float*)d_in[1];
  const float* enc    = (const float*)d_in[2];
  const float* emb_W  = (const float*)d_in[3];
  const float* emb_b  = (const float*)d_in[4];
  const float* attn_W = (const float*)d_in[5];
  const float* attn_b = (const float*)d_in[6];
  const float* comb_W = (const float*)d_in[7];
  const float* comb_b = (const float*)d_in[8];
  const float* Wih    = (const float*)d_in[9];
  const float* Whh    = (const float*)d_in[10];
  const float* bih    = (const float*)d_in[11];
  const float* bhh    = (const float*)d_in[12];
  const float* out_W  = (const float*)d_in[13];
  const float* out_b  = (const float*)d_in[14];

  float* out      = (float*)d_out;
  float* out0     = out;                    // (B,1,1)   : 2048
  float* out_h    = out + NB;               // (1,B,H)   : B*H  (e stash, then h_new)
  float* out_attn = out + NB + (size_t)NB*NH; // (B,1,L) : B*L
  float* ws_a     = (float*)d_ws;           // B*H floats: attn_applied, then xt (aliased)

  k_embed_attn<<<NB/4, 256, 0, stream>>>(x, hidden, emb_W, emb_b, attn_W, attn_b,
                                         out_h /*e stash*/, out_attn);
  k_attn_apply<<<NB, 128, 0, stream>>>(enc, out_attn, ws_a);
  k_comb<<<NB/8, 512, 0, stream>>>(out_h /*e*/, ws_a, comb_W, comb_b, ws_a /*xt*/);
  k_gru<<<NB/8, 512, 0, stream>>>(ws_a /*xt*/, hidden, Wih, Whh, bih, bhh,
                                  out_W, out_b, out0, out_h);
}

// Round 2
// 337.909 us; speedup vs baseline: 1.5352x; 1.5352x over previous
//
#include <hip/hip_runtime.h>
#include <math.h>

#define NB 2048
#define NL 256
#define NH 512

typedef unsigned short ushort_t;
typedef short s16x8 __attribute__((ext_vector_type(8)));
typedef short s16x4 __attribute__((ext_vector_type(4)));
typedef float f32x4 __attribute__((ext_vector_type(4)));

__device__ __forceinline__ float wsum(float v){
  #pragma unroll
  for (int o = 32; o; o >>= 1) v += __shfl_xor(v, o);
  return v;
}
__device__ __forceinline__ float wmax(float v){
  #pragma unroll
  for (int o = 32; o; o >>= 1) v = fmaxf(v, __shfl_xor(v, o));
  return v;
}
__device__ __forceinline__ ushort_t f2bf(float f){
  union { float f; unsigned u; } v; v.f = f;
  unsigned r = v.u + 0x7fffu + ((v.u >> 16) & 1u);
  return (ushort_t)(r >> 16);
}

// ---------------------------------------------------------------------------
// kStats0 (1 block, 64 thr): mW, mb, Su2, Suv, Sv2 of emb_W/emb_b.
// e[b][h] = alpha_b*(W[h]-mW) + beta_b*(b[h]-mb)  (rank-2 identity)
// ---------------------------------------------------------------------------
__global__ __launch_bounds__(64)
void kStats0(const float* __restrict__ eW, const float* __restrict__ eb,
             float* __restrict__ stats)
{
  const int lane = threadIdx.x;
  float sw=0, sb=0, sww=0, sbb=0, swb=0;
  #pragma unroll
  for (int k = 0; k < 8; ++k) {
    float w = eW[lane + 64*k], b = eb[lane + 64*k];
    sw += w; sb += b; sww += w*w; sbb += b*b; swb += w*b;
  }
  sw = wsum(sw); sb = wsum(sb); sww = wsum(sww); sbb = wsum(sbb); swb = wsum(swb);
  if (lane == 0) {
    float mW = sw / NH, mb = sb / NH;
    stats[0] = mW; stats[1] = mb;
    stats[2] = sww - NH*mW*mW;   // sum u^2
    stats[3] = swb - NH*mW*mb;   // sum u v
    stats[4] = sbb - NH*mb*mb;   // sum v^2
  }
}

// ---------------------------------------------------------------------------
// kStats1 (12 blocks x 64): p,q (attn_W top) and p2,q2 (comb_W top) columns.
// p[c] = sum_h u[h]*W[h][c],  q[c] = sum_h v[h]*W[h][c]
// ---------------------------------------------------------------------------
__global__ __launch_bounds__(64)
void kStats1(const float* __restrict__ eW, const float* __restrict__ eb,
             const float* __restrict__ attn_W, const float* __restrict__ comb_W,
             const float* __restrict__ stats,
             float* __restrict__ p, float* __restrict__ q,
             float* __restrict__ p2, float* __restrict__ q2)
{
  const int cx = blockIdx.x * 64 + threadIdx.x;   // 0..767
  const float mW = stats[0], mb = stats[1];
  const float* Wsrc; int ldw, c; float *op, *oq;
  if (cx < NL) { Wsrc = attn_W; ldw = NL; c = cx;     op = p  + c; oq = q  + c; }
  else         { Wsrc = comb_W; ldw = NH; c = cx - NL; op = p2 + c; oq = q2 + c; }
  float ap = 0.f, aq = 0.f;
  for (int h = 0; h < NH; ++h) {
    float w = Wsrc[(size_t)h*ldw + c];
    ap = fmaf(eW[h] - mW, w, ap);
    aq = fmaf(eb[h] - mb, w, aq);
  }
  *op = ap; *oq = aq;
}

// ---------------------------------------------------------------------------
// kAB (8 blocks x 256): per-batch (alpha, beta) from x and stats.
// ---------------------------------------------------------------------------
__global__ __launch_bounds__(256)
void kAB(const float* __restrict__ x, const float* __restrict__ stats,
         float2* __restrict__ AB)
{
  const int b = blockIdx.x * 256 + threadIdx.x;
  float xv = x[b];
  float var = (xv*xv*stats[2] + 2.f*xv*stats[3] + stats[4]) * (1.0f/NH);
  float rs = rsqrtf(var + 1e-5f);
  AB[b] = make_float2(xv * rs, rs);
}

// ---------------------------------------------------------------------------
// kH0 (512 blocks x 256): hidden fp32 -> bf16 into A_gru right half (lda 1024)
// ---------------------------------------------------------------------------
__global__ __launch_bounds__(256)
void kH0(const float* __restrict__ hidden, ushort_t* __restrict__ A2)
{
  const int idx = (blockIdx.x * 256 + threadIdx.x) * 8;  // flat over B*H
  const int b = idx >> 9, h = idx & 511;
  float4 v0 = *(const float4*)(hidden + idx);
  float4 v1 = *(const float4*)(hidden + idx + 4);
  s16x8 o;
  o[0]=f2bf(v0.x); o[1]=f2bf(v0.y); o[2]=f2bf(v0.z); o[3]=f2bf(v0.w);
  o[4]=f2bf(v1.x); o[5]=f2bf(v1.y); o[6]=f2bf(v1.z); o[7]=f2bf(v1.w);
  *(s16x8*)&A2[(size_t)b*1024 + 512 + h] = o;
}

// ---------------------------------------------------------------------------
// T_WB: transpose+bf16 bottom half of attn_W/comb_W: dst[c][k] (ld 512)
// grid (C/64, 8), block 256
// ---------------------------------------------------------------------------
__global__ __launch_bounds__(256)
void T_WB(const float* __restrict__ src, int C, ushort_t* __restrict__ dst)
{
  const int c = blockIdx.x * 64 + (threadIdx.x & 63);
  const int ksub = blockIdx.y * 64 + (threadIdx.x >> 6) * 16;
  ushort_t vals[16];
  #pragma unroll
  for (int kk = 0; kk < 16; ++kk)
    vals[kk] = f2bf(src[(size_t)(ksub + kk) * C + c]);
  *(s16x8*)&dst[(size_t)c*512 + ksub]     = *(s16x8*)&vals[0];
  *(s16x8*)&dst[(size_t)c*512 + ksub + 8] = *(s16x8*)&vals[8];
}

// ---------------------------------------------------------------------------
// T_gru: build gate-interleaved transposed blockdiag weight Wt[2048][1024] bf16
// dst row n: g=n>>6 (16-col group), t=(n>>4)&3 (gate r,z,in,hn), c=16g+(n&15)
// Wt[n][k] = k<512 ? (t==3?0:Wih[k][sc]) : (t==2?0:Whh[k-512][sc])
// sc = t==0? c : t==1? 512+c : 1024+c.   grid (32,16), block 256
// ---------------------------------------------------------------------------
__global__ __launch_bounds__(256)
void T_gru(const float* __restrict__ Wih, const float* __restrict__ Whh,
           ushort_t* __restrict__ dst)
{
  const int n = blockIdx.x * 64 + (threadIdx.x & 63);
  const int ksub = blockIdx.y * 64 + (threadIdx.x >> 6) * 16;
  const int g = n >> 6, t = (n >> 4) & 3, c = (g << 4) | (n & 15);
  const int sc = (t == 0) ? c : (t == 1) ? (512 + c) : (1024 + c);
  ushort_t vals[16];
  #pragma unroll
  for (int kk = 0; kk < 16; ++kk) {
    int k = ksub + kk;
    float v;
    if (k < 512) v = (t == 3) ? 0.f : Wih[(size_t)k*1536 + sc];
    else         v = (t == 2) ? 0.f : Whh[(size_t)(k-512)*1536 + sc];
    vals[kk] = f2bf(v);
  }
  *(s16x8*)&dst[(size_t)n*1024 + ksub]     = *(s16x8*)&vals[0];
  *(s16x8*)&dst[(size_t)n*1024 + ksub + 8] = *(s16x8*)&vals[8];
}

// ---------------------------------------------------------------------------
// gemm_bf16<EPI>: C(128x128 tile) = A[M][K]bf16 @ Bt[N][K]bf16^T
// 256 thr = 4 waves (2x2), each wave 64x64 = 4x4 frags of 16x16x32 MFMA.
// EPI 1: logits += attn_b + a*p + b*q -> fp32 (ld 256)
// EPI 2: xt = relu(acc + comb_b + a*p2 + b*q2) -> bf16 at out_bf (ld 1024)
// EPI 3: GRU gates (j = gate index) -> h_new fp32 (ld 512)
// ---------------------------------------------------------------------------
template<int EPI>
__global__ __launch_bounds__(256)
void gemm_bf16(const ushort_t* __restrict__ A, int lda,
               const ushort_t* __restrict__ Bt, int K,
               const float2* __restrict__ AB,
               const float* __restrict__ pvec, const float* __restrict__ qvec,
               const float* __restrict__ bias,
               float* __restrict__ out_f,
               ushort_t* __restrict__ out_bf,
               const float* __restrict__ bih, const float* __restrict__ bhh,
               const float* __restrict__ hidden)
{
  __shared__ ushort_t As[128][72];
  __shared__ ushort_t Bs[128][72];
  const int tid = threadIdx.x;
  const int lane = tid & 63;
  const int wv = tid >> 6;
  const int wr = wv >> 1, wc = wv & 1;
  const int m0 = blockIdx.x * 128, n0 = blockIdx.y * 128;

  f32x4 acc[4][4];
  #pragma unroll
  for (int i = 0; i < 4; ++i)
    #pragma unroll
    for (int j = 0; j < 4; ++j)
      acc[i][j] = (f32x4){0.f, 0.f, 0.f, 0.f};

  const int srow = tid >> 3;          // 0..31
  const int scol = (tid & 7) * 8;     // 0..56

  for (int kt = 0; kt < K; kt += 64) {
    __syncthreads();
    #pragma unroll
    for (int it = 0; it < 4; ++it) {
      const int r = srow + it * 32;
      *(s16x8*)&As[r][scol] = *(const s16x8*)&A [(size_t)(m0 + r)*lda + kt + scol];
      *(s16x8*)&Bs[r][scol] = *(const s16x8*)&Bt[(size_t)(n0 + r)*K   + kt + scol];
    }
    __syncthreads();
    #pragma unroll
    for (int ks = 0; ks < 2; ++ks) {
      s16x8 af[4], bfr[4];
      const int ko = ks * 32 + (lane >> 4) * 8;
      #pragma unroll
      for (int f = 0; f < 4; ++f) {
        af[f]  = *(const s16x8*)&As[wr*64 + f*16 + (lane & 15)][ko];
        bfr[f] = *(const s16x8*)&Bs[wc*64 + f*16 + (lane & 15)][ko];
      }
      #pragma unroll
      for (int i = 0; i < 4; ++i)
        #pragma unroll
        for (int j = 0; j < 4; ++j)
          acc[i][j] = __builtin_amdgcn_mfma_f32_16x16x32_bf16(af[i], bfr[j], acc[i][j], 0, 0, 0);
    }
  }

  // ---- epilogue: D layout col=lane&15, row=(lane>>4)*4+reg (m89-verified)
  if constexpr (EPI == 1 || EPI == 2) {
    #pragma unroll
    for (int i = 0; i < 4; ++i) {
      #pragma unroll
      for (int reg = 0; reg < 4; ++reg) {
        const int row = m0 + wr*64 + i*16 + ((lane >> 4) << 2) + reg;
        const float2 ab = AB[row];
        #pragma unroll
        for (int j = 0; j < 4; ++j) {
          const int col = n0 + wc*64 + j*16 + (lane & 15);
          float v = acc[i][j][reg] + bias[col] + ab.x*pvec[col] + ab.y*qvec[col];
          if constexpr (EPI == 1) out_f[(size_t)row*NL + col] = v;
          else                    out_bf[(size_t)row*1024 + col] = f2bf(fmaxf(v, 0.f));
        }
      }
    }
  } else {  // EPI == 3: GRU gates.  j: 0=r 1=z 2=i_n 3=h_n
    const int g = (n0 >> 6) + wc;
    const int hcol = (g << 4) | (lane & 15);
    const float b_r = bih[hcol]       + bhh[hcol];
    const float b_z = bih[512 + hcol] + bhh[512 + hcol];
    const float b_i = bih[1024 + hcol];
    const float b_h = bhh[1024 + hcol];
    #pragma unroll
    for (int i = 0; i < 4; ++i) {
      #pragma unroll
      for (int reg = 0; reg < 4; ++reg) {
        const int row = m0 + wr*64 + i*16 + ((lane >> 4) << 2) + reg;
        float rv = 1.f / (1.f + expf(-(acc[i][0][reg] + b_r)));
        float zv = 1.f / (1.f + expf(-(acc[i][1][reg] + b_z)));
        float nv = tanhf(acc[i][2][reg] + b_i + rv * (acc[i][3][reg] + b_h));
        float h0v = hidden[(size_t)row*NH + hcol];
        out_f[(size_t)row*NH + hcol] = nv + zv * (h0v - nv);
      }
    }
  }
}

// ---------------------------------------------------------------------------
// kSoftmax (512 blocks x 256): wave per row over L=256, fp32 -> d_out attn
// ---------------------------------------------------------------------------
__global__ __launch_bounds__(256)
void kSoftmax(const float* __restrict__ logits, float* __restrict__ attn_out)
{
  const int row = blockIdx.x * 4 + (threadIdx.x >> 6);
  const int lane = threadIdx.x & 63;
  float4 v = ((const float4*)(logits + (size_t)row*NL))[lane];
  float m = wmax(fmaxf(fmaxf(v.x, v.y), fmaxf(v.z, v.w)));
  v.x = expf(v.x - m); v.y = expf(v.y - m); v.z = expf(v.z - m); v.w = expf(v.w - m);
  float inv = 1.f / wsum(v.x + v.y + v.z + v.w);
  v.x *= inv; v.y *= inv; v.z *= inv; v.w *= inv;
  ((float4*)(attn_out + (size_t)row*NL))[lane] = v;
}

// ---------------------------------------------------------------------------
// k2: attn_applied (bf16) = sum_l w[b,l] * enc[b,l,:]. 1.07 GB HBM stream.
// ---------------------------------------------------------------------------
__global__ __launch_bounds__(128)
void k_attn_apply(const float* __restrict__ enc, const float* __restrict__ aw,
                  ushort_t* __restrict__ abf)
{
  __shared__ float w[NL];
  const int tid = threadIdx.x;
  const int b = blockIdx.x;
  for (int l = tid; l < NL; l += 128) w[l] = aw[(size_t)b*NL + l];
  __syncthreads();
  const float4* ep = (const float4*)(enc + (size_t)b*NL*NH);
  float4 acc = {0.f, 0.f, 0.f, 0.f};
  #pragma unroll 4
  for (int l = 0; l < NL; ++l) {
    float wv = w[l];
    float4 e = ep[l*(NH/4) + tid];
    acc.x = fmaf(wv, e.x, acc.x); acc.y = fmaf(wv, e.y, acc.y);
    acc.z = fmaf(wv, e.z, acc.z); acc.w = fmaf(wv, e.w, acc.w);
  }
  s16x4 o; o[0]=f2bf(acc.x); o[1]=f2bf(acc.y); o[2]=f2bf(acc.z); o[3]=f2bf(acc.w);
  *(s16x4*)&abf[(size_t)b*NH + tid*4] = o;
}

// ---------------------------------------------------------------------------
// kOut (512 blocks x 256): out0[b] = dot(h_new[b], out_W) + out_b
// ---------------------------------------------------------------------------
__global__ __launch_bounds__(256)
void kOut(const float* __restrict__ h, const float* __restrict__ out_W,
          const float* __restrict__ out_b, float* __restrict__ out0)
{
  const int row = blockIdx.x * 4 + (threadIdx.x >> 6);
  const int lane = threadIdx.x & 63;
  const float4* hp = (const float4*)(h + (size_t)row*NH);
  const float4* wp = (const float4*)out_W;
  float4 h1 = hp[lane*2], h2 = hp[lane*2+1];
  float4 w1 = wp[lane*2], w2 = wp[lane*2+1];
  float d = h1.x*w1.x + h1.y*w1.y + h1.z*w1.z + h1.w*w1.w
          + h2.x*w2.x + h2.y*w2.y + h2.z*w2.z + h2.w*w2.w;
  d = wsum(d);
  if (lane == 0) out0[row] = d + out_b[0];
}

// ---------------------------------------------------------------------------
extern "C" void kernel_launch(void* const* d_in, const int* in_sizes, int n_in,
                              void* d_out, int out_size, void* d_ws, size_t ws_size,
                              hipStream_t stream)
{
  const float* x      = (const float*)d_in[0];
  const float* hidden = (const float*)d_in[1];
  const float* enc    = (const float*)d_in[2];
  const float* emb_W  = (const float*)d_in[3];
  const float* emb_b  = (const float*)d_in[4];
  const float* attn_W = (const float*)d_in[5];
  const float* attn_b = (const float*)d_in[6];
  const float* comb_W = (const float*)d_in[7];
  const float* comb_b = (const float*)d_in[8];
  const float* Wih    = (const float*)d_in[9];
  const float* Whh    = (const float*)d_in[10];
  const float* bih    = (const float*)d_in[11];
  const float* bhh    = (const float*)d_in[12];
  const float* out_W  = (const float*)d_in[13];
  const float* out_b  = (const float*)d_in[14];

  float* out      = (float*)d_out;
  float* out0     = out;                          // 2048
  float* out_h    = out + NB;                     // B*H
  float* out_attn = out + NB + (size_t)NB*NH;     // B*L

  float* wsf    = (float*)d_ws;
  float* stats  = wsf;            // 16
  float* p      = wsf + 16;       // 256
  float* q      = wsf + 272;      // 256
  float* p2     = wsf + 528;      // 512
  float* q2     = wsf + 1040;     // 512 (end 1552)
  float2* AB    = (float2*)(wsf + 1600);  // 2048 float2
  float* logits = wsf + 5760;             // 2048*256
  ushort_t* usb = (ushort_t*)(wsf + 530048);
  ushort_t* A2  = usb;                    // [2048][1024] bf16: [xt | h0]
  ushort_t* ABF = usb + 2097152;          // [2048][512]  bf16: attn_applied
  ushort_t* WTA = usb + 3145728;          // [256][512]
  ushort_t* WTC = usb + 3276800;          // [512][512]
  ushort_t* WTG = usb + 3538944;          // [2048][1024]

  kStats0<<<1, 64, 0, stream>>>(emb_W, emb_b, stats);
  kStats1<<<12, 64, 0, stream>>>(emb_W, emb_b, attn_W, comb_W, stats, p, q, p2, q2);
  kAB<<<8, 256, 0, stream>>>(x, stats, AB);
  kH0<<<512, 256, 0, stream>>>(hidden, A2);
  T_WB<<<dim3(4, 8), 256, 0, stream>>>(attn_W + 512*NL, NL, WTA);
  T_WB<<<dim3(8, 8), 256, 0, stream>>>(comb_W + 512*NH, NH, WTC);
  T_gru<<<dim3(32, 16), 256, 0, stream>>>(Wih, Whh, WTG);

  // logits = h0 @ attn_W_bot + rank2 + bias   (M=2048, N=256, K=512)
  gemm_bf16<1><<<dim3(16, 2), 256, 0, stream>>>(A2 + 512, 1024, WTA, 512,
      AB, p, q, attn_b, logits, nullptr, nullptr, nullptr, nullptr);
  kSoftmax<<<512, 256, 0, stream>>>(logits, out_attn);
  k_attn_apply<<<NB, 128, 0, stream>>>(enc, out_attn, ABF);
  // xt = relu(a @ comb_W_bot + rank2 + bias) -> A2 left (M=2048,N=512,K=512)
  gemm_bf16<2><<<dim3(16, 4), 256, 0, stream>>>(ABF, 512, WTC, 512,
      AB, p2, q2, comb_b, nullptr, A2, nullptr, nullptr, nullptr);
  // GRU: [xt|h0] @ WTG^T + gate epilogue -> h_new (M=2048,N=2048,K=1024)
  gemm_bf16<3><<<dim3(16, 16), 256, 0, stream>>>(A2, 1024, WTG, 1024,
      nullptr, nullptr, nullptr, nullptr, out_h, nullptr, bih, bhh, hidden);
  kOut<<<512, 256, 0, stream>>>(out_h, out_W, out_b, out0);
}

// Round 3
// 298.969 us; speedup vs baseline: 1.7351x; 1.1302x over previous
//
#include <hip/hip_runtime.h>
#include <math.h>

#define NB 2048
#define NL 256
#define NH 512

typedef unsigned short ushort_t;
typedef short s16x8 __attribute__((ext_vector_type(8)));
typedef short s16x4 __attribute__((ext_vector_type(4)));
typedef float f32x4 __attribute__((ext_vector_type(4)));

__device__ __forceinline__ float wsum(float v){
  #pragma unroll
  for (int o = 32; o; o >>= 1) v += __shfl_xor(v, o);
  return v;
}
__device__ __forceinline__ float wmax(float v){
  #pragma unroll
  for (int o = 32; o; o >>= 1) v = fmaxf(v, __shfl_xor(v, o));
  return v;
}
__device__ __forceinline__ ushort_t f2bf(float f){
  union { float f; unsigned u; } v; v.f = f;
  unsigned r = v.u + 0x7fffu + ((v.u >> 16) & 1u);
  return (ushort_t)(r >> 16);
}
__device__ __forceinline__ float bf2f(short s){
  union { unsigned u; float f; } v; v.u = ((unsigned)(unsigned short)s) << 16;
  return v.f;
}

// ---------------------------------------------------------------------------
// kPrep (13 blocks x 256): blocks 0-3 p,q (attn top); 4-11 p2,q2 (comb top);
// block 12: stats = {mW, mb, Su2, Suv, Sv2}. Each block recomputes mW,mb.
// ---------------------------------------------------------------------------
__global__ __launch_bounds__(256)
void kPrep(const float* __restrict__ eW, const float* __restrict__ eb,
           const float* __restrict__ attn_W, const float* __restrict__ comb_W,
           float* __restrict__ stats,
           float* __restrict__ p, float* __restrict__ q,
           float* __restrict__ p2, float* __restrict__ q2)
{
  __shared__ float rw[4], rb[4];
  __shared__ float pa[4][64], pb[4][64];
  const int tid = threadIdx.x, lane = tid & 63, wv = tid >> 6;
  const int bid = blockIdx.x;
  float swv = eW[tid] + eW[tid + 256];
  float sbv = eb[tid] + eb[tid + 256];
  swv = wsum(swv); sbv = wsum(sbv);
  if (lane == 0) { rw[wv] = swv; rb[wv] = sbv; }
  __syncthreads();
  const float mW = (rw[0]+rw[1]+rw[2]+rw[3]) * (1.f/NH);
  const float mb = (rb[0]+rb[1]+rb[2]+rb[3]) * (1.f/NH);

  if (bid == 12) {
    float u0 = eW[tid]-mW, u1 = eW[tid+256]-mW;
    float v0 = eb[tid]-mb, v1 = eb[tid+256]-mb;
    float s2 = u0*u0 + u1*u1, s3 = u0*v0 + u1*v1, s4 = v0*v0 + v1*v1;
    s2 = wsum(s2); s3 = wsum(s3); s4 = wsum(s4);
    if (lane == 0) { pa[0][wv] = s2; pa[1][wv] = s3; pa[2][wv] = s4; }
    __syncthreads();
    if (tid == 0) {
      stats[0] = mW; stats[1] = mb;
      stats[2] = pa[0][0]+pa[0][1]+pa[0][2]+pa[0][3];
      stats[3] = pa[1][0]+pa[1][1]+pa[1][2]+pa[1][3];
      stats[4] = pa[2][0]+pa[2][1]+pa[2][2]+pa[2][3];
    }
    return;
  }
  const float* Wsrc; int ldw, c0; float *op, *oq;
  if (bid < 4) { Wsrc = attn_W; ldw = NL; c0 = bid*64;     op = p  + c0; oq = q  + c0; }
  else         { Wsrc = comb_W; ldw = NH; c0 = (bid-4)*64; op = p2 + c0; oq = q2 + c0; }
  const int c = c0 + lane;
  const int hc = tid >> 6;
  float ap = 0.f, aq = 0.f;
  for (int h = hc*128; h < hc*128 + 128; ++h) {
    float w = Wsrc[(size_t)h*ldw + c];
    ap = fmaf(eW[h]-mW, w, ap);
    aq = fmaf(eb[h]-mb, w, aq);
  }
  pa[hc][lane] = ap; pb[hc][lane] = aq;
  __syncthreads();
  if (hc == 0) {
    op[lane] = pa[0][lane]+pa[1][lane]+pa[2][lane]+pa[3][lane];
    oq[lane] = pb[0][lane]+pb[1][lane]+pb[2][lane]+pb[3][lane];
  }
}

// ---------------------------------------------------------------------------
// kPrepB (1120 blocks x 256): branch-fused prep.
//  bid <  512: hidden fp32 -> bf16 into A2 right half (lda 1024)
//  bid <  544: WTA[c][k] = bf16(attn_W_bottom^T)  (256x512)
//  bid <  608: WTC[c][k] = bf16(comb_W_bottom^T)  (512x512)
//  else      : WTG[n][k] gate-interleaved blockdiag GRU weight (2048x1024)
// ---------------------------------------------------------------------------
__global__ __launch_bounds__(256)
void kPrepB(const float* __restrict__ hidden,
            const float* __restrict__ attn_W, const float* __restrict__ comb_W,
            const float* __restrict__ Wih, const float* __restrict__ Whh,
            ushort_t* __restrict__ A2, ushort_t* __restrict__ WTA,
            ushort_t* __restrict__ WTC, ushort_t* __restrict__ WTG)
{
  const int bid = blockIdx.x, tid = threadIdx.x;
  if (bid < 512) {
    const int idx = (bid*256 + tid) * 8;
    const int b = idx >> 9, h = idx & 511;
    float4 v0 = *(const float4*)(hidden + idx);
    float4 v1 = *(const float4*)(hidden + idx + 4);
    s16x8 o;
    o[0]=f2bf(v0.x); o[1]=f2bf(v0.y); o[2]=f2bf(v0.z); o[3]=f2bf(v0.w);
    o[4]=f2bf(v1.x); o[5]=f2bf(v1.y); o[6]=f2bf(v1.z); o[7]=f2bf(v1.w);
    *(s16x8*)&A2[(size_t)b*1024 + 512 + h] = o;
    return;
  }
  if (bid < 544) {
    const int b2 = bid - 512, bx = b2 & 3, by = b2 >> 2;
    const int c = bx*64 + (tid & 63);
    const int ksub = by*64 + (tid >> 6)*16;
    ushort_t vals[16];
    #pragma unroll
    for (int kk = 0; kk < 16; ++kk)
      vals[kk] = f2bf(attn_W[(size_t)(512 + ksub + kk)*NL + c]);
    *(s16x8*)&WTA[(size_t)c*512 + ksub]     = *(s16x8*)&vals[0];
    *(s16x8*)&WTA[(size_t)c*512 + ksub + 8] = *(s16x8*)&vals[8];
    return;
  }
  if (bid < 608) {
    const int b2 = bid - 544, bx = b2 & 7, by = b2 >> 3;
    const int c = bx*64 + (tid & 63);
    const int ksub = by*64 + (tid >> 6)*16;
    ushort_t vals[16];
    #pragma unroll
    for (int kk = 0; kk < 16; ++kk)
      vals[kk] = f2bf(comb_W[(size_t)(512 + ksub + kk)*NH + c]);
    *(s16x8*)&WTC[(size_t)c*512 + ksub]     = *(s16x8*)&vals[0];
    *(s16x8*)&WTC[(size_t)c*512 + ksub + 8] = *(s16x8*)&vals[8];
    return;
  }
  {
    const int b2 = bid - 608, bx = b2 & 31, by = b2 >> 5;
    const int n = bx*64 + (tid & 63);
    const int ksub = by*64 + (tid >> 6)*16;
    const int g = n >> 6, t = (n >> 4) & 3, c = (g << 4) | (n & 15);
    const int sc = (t == 0) ? c : (t == 1) ? (512 + c) : (1024 + c);
    ushort_t vals[16];
    #pragma unroll
    for (int kk = 0; kk < 16; ++kk) {
      int k = ksub + kk;
      float v;
      if (k < 512) v = (t == 3) ? 0.f : Wih[(size_t)k*1536 + sc];
      else         v = (t == 2) ? 0.f : Whh[(size_t)(k-512)*1536 + sc];
      vals[kk] = f2bf(v);
    }
    *(s16x8*)&WTG[(size_t)n*1024 + ksub]     = *(s16x8*)&vals[0];
    *(s16x8*)&WTG[(size_t)n*1024 + ksub + 8] = *(s16x8*)&vals[8];
  }
}

// ---------------------------------------------------------------------------
// k2fused (2048 blocks x 128): per batch b:
//   phase A: logits[256] = h0 . WTA^T + attn_b + rank2(e)  (bf16 weights, L2)
//   softmax in LDS -> attn_out (d_out) + wl
//   phase B: attn_applied = sum_l wl[l]*enc[b,l,:]  (the 1.07 GB HBM stream)
// ---------------------------------------------------------------------------
__global__ __launch_bounds__(128)
void k2fused(const float* __restrict__ x, const float* __restrict__ hidden,
             const float* __restrict__ enc, const ushort_t* __restrict__ WTA,
             const float* __restrict__ attn_b,
             const float* __restrict__ p, const float* __restrict__ q,
             const float* __restrict__ stats,
             float* __restrict__ attn_out, ushort_t* __restrict__ abf)
{
  __shared__ __align__(16) float h0s[NH];
  __shared__ float wl[NL];
  __shared__ float sred[2];
  const int tid = threadIdx.x, lane = tid & 63, wv = tid >> 6;
  const int b = blockIdx.x;

  ((float4*)h0s)[tid] = ((const float4*)(hidden + (size_t)b*NH))[tid];
  __syncthreads();

  const float xv = x[b];
  const float rs = rsqrtf((xv*xv*stats[2] + 2.f*xv*stats[3] + stats[4])*(1.0f/NH) + 1e-5f);
  float lg[2];
  #pragma unroll
  for (int cc = 0; cc < 2; ++cc) {
    const int c = tid + cc*128;
    const ushort_t* wrow = WTA + (size_t)c*512;
    float acc = 0.f;
    #pragma unroll 4
    for (int k = 0; k < NH; k += 8) {
      s16x8 w = *(const s16x8*)&wrow[k];
      #pragma unroll
      for (int jj = 0; jj < 8; ++jj)
        acc = fmaf(bf2f(w[jj]), h0s[k+jj], acc);
    }
    lg[cc] = acc + attn_b[c] + xv*rs*p[c] + rs*q[c];
  }
  // block softmax (256 vals over 128 threads / 2 waves)
  float m = wmax(fmaxf(lg[0], lg[1]));
  if (lane == 0) sred[wv] = m;
  __syncthreads();
  m = fmaxf(sred[0], sred[1]);
  __syncthreads();
  float e0 = expf(lg[0]-m), e1 = expf(lg[1]-m);
  float s = wsum(e0 + e1);
  if (lane == 0) sred[wv] = s;
  __syncthreads();
  const float inv = 1.f / (sred[0] + sred[1]);
  e0 *= inv; e1 *= inv;
  wl[tid] = e0; wl[tid+128] = e1;
  attn_out[(size_t)b*NL + tid]       = e0;
  attn_out[(size_t)b*NL + tid + 128] = e1;
  __syncthreads();

  const float4* ep = (const float4*)(enc + (size_t)b*NL*NH);
  float4 acc = {0.f,0.f,0.f,0.f};
  #pragma unroll 4
  for (int l = 0; l < NL; ++l) {
    float wv2 = wl[l];
    float4 e = ep[l*(NH/4) + tid];
    acc.x = fmaf(wv2,e.x,acc.x); acc.y = fmaf(wv2,e.y,acc.y);
    acc.z = fmaf(wv2,e.z,acc.z); acc.w = fmaf(wv2,e.w,acc.w);
  }
  s16x4 o; o[0]=f2bf(acc.x); o[1]=f2bf(acc.y); o[2]=f2bf(acc.z); o[3]=f2bf(acc.w);
  *(s16x4*)&abf[(size_t)b*NH + tid*4] = o;
}

// ---------------------------------------------------------------------------
// gemm_bf16<EPI>: 128x64 tile, 4 waves (4x1), wave = 32x64 (2x4 frags).
// EPI 2: xt = relu(acc + comb_b + rank2) -> bf16 at A2 left (ld 1024)
// EPI 3: GRU gates (j = gate) -> h_new fp32
// ---------------------------------------------------------------------------
template<int EPI>
__global__ __launch_bounds__(256)
void gemm_bf16(const ushort_t* __restrict__ A, int lda,
               const ushort_t* __restrict__ Bt, int K,
               const float* __restrict__ xin, const float* __restrict__ stats,
               const float* __restrict__ pvec, const float* __restrict__ qvec,
               const float* __restrict__ bias,
               ushort_t* __restrict__ out_bf,
               const float* __restrict__ bih, const float* __restrict__ bhh,
               const float* __restrict__ hidden, float* __restrict__ h_out)
{
  __shared__ ushort_t As[128][72];
  __shared__ ushort_t Bs[64][72];
  const int tid = threadIdx.x, lane = tid & 63, wr = tid >> 6;
  const int m0 = blockIdx.x * 128, n0 = blockIdx.y * 64;

  f32x4 acc[2][4];
  #pragma unroll
  for (int i = 0; i < 2; ++i)
    #pragma unroll
    for (int j = 0; j < 4; ++j)
      acc[i][j] = (f32x4){0.f,0.f,0.f,0.f};

  const int srow = tid >> 3, scol = (tid & 7) * 8;
  for (int kt = 0; kt < K; kt += 64) {
    __syncthreads();
    #pragma unroll
    for (int it = 0; it < 4; ++it) {
      const int r = srow + it*32;
      *(s16x8*)&As[r][scol] = *(const s16x8*)&A[(size_t)(m0+r)*lda + kt + scol];
    }
    #pragma unroll
    for (int it = 0; it < 2; ++it) {
      const int r = srow + it*32;
      *(s16x8*)&Bs[r][scol] = *(const s16x8*)&Bt[(size_t)(n0+r)*K + kt + scol];
    }
    __syncthreads();
    #pragma unroll
    for (int ks = 0; ks < 2; ++ks) {
      const int ko = ks*32 + (lane >> 4)*8;
      s16x8 af[2], bfr[4];
      #pragma unroll
      for (int i = 0; i < 2; ++i) af[i]  = *(const s16x8*)&As[wr*32 + i*16 + (lane & 15)][ko];
      #pragma unroll
      for (int j = 0; j < 4; ++j) bfr[j] = *(const s16x8*)&Bs[j*16 + (lane & 15)][ko];
      #pragma unroll
      for (int i = 0; i < 2; ++i)
        #pragma unroll
        for (int j = 0; j < 4; ++j)
          acc[i][j] = __builtin_amdgcn_mfma_f32_16x16x32_bf16(af[i], bfr[j], acc[i][j], 0, 0, 0);
    }
  }

  if constexpr (EPI == 2) {
    const float S2 = stats[2], S3 = stats[3], S4 = stats[4];
    #pragma unroll
    for (int i = 0; i < 2; ++i) {
      #pragma unroll
      for (int reg = 0; reg < 4; ++reg) {
        const int row = m0 + wr*32 + i*16 + ((lane >> 4) << 2) + reg;
        const float xv = xin[row];
        const float rs = rsqrtf((xv*xv*S2 + 2.f*xv*S3 + S4)*(1.0f/NH) + 1e-5f);
        const float al = xv*rs, be = rs;
        #pragma unroll
        for (int j = 0; j < 4; ++j) {
          const int col = n0 + j*16 + (lane & 15);
          float v = acc[i][j][reg] + bias[col] + al*pvec[col] + be*qvec[col];
          out_bf[(size_t)row*1024 + col] = f2bf(fmaxf(v, 0.f));
        }
      }
    }
  } else {  // EPI 3
    const int g = n0 >> 6;
    const int hcol = (g << 4) | (lane & 15);
    const float b_r = bih[hcol]        + bhh[hcol];
    const float b_z = bih[512 + hcol]  + bhh[512 + hcol];
    const float b_i = bih[1024 + hcol];
    const float b_h = bhh[1024 + hcol];
    #pragma unroll
    for (int i = 0; i < 2; ++i) {
      #pragma unroll
      for (int reg = 0; reg < 4; ++reg) {
        const int row = m0 + wr*32 + i*16 + ((lane >> 4) << 2) + reg;
        float rv = 1.f / (1.f + expf(-(acc[i][0][reg] + b_r)));
        float zv = 1.f / (1.f + expf(-(acc[i][1][reg] + b_z)));
        float nv = tanhf(acc[i][2][reg] + b_i + rv * (acc[i][3][reg] + b_h));
        float h0v = hidden[(size_t)row*NH + hcol];
        h_out[(size_t)row*NH + hcol] = nv + zv * (h0v - nv);
      }
    }
  }
}

// ---------------------------------------------------------------------------
// kOut (512 blocks x 256): out0[b] = dot(h_new[b], out_W) + out_b
// ---------------------------------------------------------------------------
__global__ __launch_bounds__(256)
void kOut(const float* __restrict__ h, const float* __restrict__ out_W,
          const float* __restrict__ out_b, float* __restrict__ out0)
{
  const int row = blockIdx.x * 4 + (threadIdx.x >> 6);
  const int lane = threadIdx.x & 63;
  const float4* hp = (const float4*)(h + (size_t)row*NH);
  const float4* wp = (const float4*)out_W;
  float4 h1 = hp[lane*2], h2 = hp[lane*2+1];
  float4 w1 = wp[lane*2], w2 = wp[lane*2+1];
  float d = h1.x*w1.x + h1.y*w1.y + h1.z*w1.z + h1.w*w1.w
          + h2.x*w2.x + h2.y*w2.y + h2.z*w2.z + h2.w*w2.w;
  d = wsum(d);
  if (lane == 0) out0[row] = d + out_b[0];
}

// ---------------------------------------------------------------------------
extern "C" void kernel_launch(void* const* d_in, const int* in_sizes, int n_in,
                              void* d_out, int out_size, void* d_ws, size_t ws_size,
                              hipStream_t stream)
{
  const float* x      = (const float*)d_in[0];
  const float* hidden = (const float*)d_in[1];
  const float* enc    = (const float*)d_in[2];
  const float* emb_W  = (const float*)d_in[3];
  const float* emb_b  = (const float*)d_in[4];
  const float* attn_W = (const float*)d_in[5];
  const float* attn_b = (const float*)d_in[6];
  const float* comb_W = (const float*)d_in[7];
  const float* comb_b = (const float*)d_in[8];
  const float* Wih    = (const float*)d_in[9];
  const float* Whh    = (const float*)d_in[10];
  const float* bih    = (const float*)d_in[11];
  const float* bhh    = (const float*)d_in[12];
  const float* out_W  = (const float*)d_in[13];
  const float* out_b  = (const float*)d_in[14];

  float* out      = (float*)d_out;
  float* out0     = out;                          // 2048
  float* out_h    = out + NB;                     // B*H
  float* out_attn = out + NB + (size_t)NB*NH;     // B*L

  float* wsf   = (float*)d_ws;
  float* stats = wsf;            // 16
  float* p     = wsf + 16;       // 256
  float* q     = wsf + 272;      // 256
  float* p2    = wsf + 528;      // 512
  float* q2    = wsf + 1040;     // 512 (end 1552)
  ushort_t* usb = (ushort_t*)(wsf + 1600);
  ushort_t* A2  = usb;                    // [2048][1024] bf16: [xt | h0]
  ushort_t* ABF = usb + 2097152;          // [2048][512]  bf16: attn_applied
  ushort_t* WTA = usb + 3145728;          // [256][512]
  ushort_t* WTC = usb + 3276800;          // [512][512]
  ushort_t* WTG = usb + 3538944;          // [2048][1024]

  kPrep<<<13, 256, 0, stream>>>(emb_W, emb_b, attn_W, comb_W, stats, p, q, p2, q2);
  kPrepB<<<1120, 256, 0, stream>>>(hidden, attn_W, comb_W, Wih, Whh, A2, WTA, WTC, WTG);
  k2fused<<<NB, 128, 0, stream>>>(x, hidden, enc, WTA, attn_b, p, q, stats,
                                  out_attn, ABF);
  // xt = relu(a @ comb_W_bot + rank2 + bias) -> A2 left (M=2048,N=512,K=512)
  gemm_bf16<2><<<dim3(16, 8), 256, 0, stream>>>(ABF, 512, WTC, 512,
      x, stats, p2, q2, comb_b, A2, nullptr, nullptr, nullptr, nullptr);
  // GRU: [xt|h0] @ WTG^T + gate epilogue -> h_new (M=2048,N=2048,K=1024)
  gemm_bf16<3><<<dim3(16, 32), 256, 0, stream>>>(A2, 1024, WTG, 1024,
      nullptr, nullptr, nullptr, nullptr, nullptr, nullptr, bih, bhh, hidden, out_h);
  kOut<<<512, 256, 0, stream>>>(out_h, out_W, out_b, out0);
}